// Round 1
// baseline (561.481 us; speedup 1.0000x reference)
//
#include <hip/hip_runtime.h>

// Fused per-sample dynamic conv network, fp32.
// x: (8,3,1024,1024), thumb: (8,3,256,256), feature: (8,492)
// out = [x_out flat, thumb flat]
//
// One block = one 32x32 output tile of one sample. Halo 5 (five 3x3 convs).
// LDS ping-pong buffers 3x42x42 fp32; valid region shrinks by 1 per layer.
// conv1x1 + global residual + attention fused into epilogue (no extra pass).

#define TILE 32
#define BUFW 42
#define BUFP (BUFW*BUFW)      // 1764
#define BUFE (3*BUFP)         // 5292

__global__ __launch_bounds__(256) void fused_net(
    const float* __restrict__ xin,
    const float* __restrict__ feat,
    float* __restrict__ out)
{
    const int tid = threadIdx.x;
    const int gx0 = blockIdx.x * TILE;
    const int gy0 = blockIdx.y * TILE;
    const int b   = blockIdx.z;
    const float* wf = feat + b * 492;   // uniform -> scalar loads

    __shared__ float lds[2 * BUFE + 16];
    float* bufA = lds;
    float* bufB = lds + BUFE + 8;       // pad keeps 16B alignment, absorbs benign OOB window reads

    // ---- stage input tile (halo 5, zero outside image) ----
    const float* xb = xin + ((size_t)(b * 3) << 20);
    for (int idx = tid; idx < BUFE; idx += 256) {
        int ch  = idx / BUFP;
        int rem = idx - ch * BUFP;
        int yy  = rem / BUFW;
        int xx  = rem - yy * BUFW;
        int gy = gy0 - 5 + yy, gx = gx0 - 5 + xx;
        float v = 0.f;
        if ((unsigned)gy < 1024u && (unsigned)gx < 1024u)
            v = xb[(ch << 20) + (gy << 10) + gx];
        bufA[idx] = v;
    }
    __syncthreads();

    // ---- residual (original x) for this thread's 4 fixed output pixels ----
    const int row  = tid >> 3;          // 0..31
    const int colb = (tid & 7) << 2;    // 0,4,...,28
    float res[3][4];
    #pragma unroll
    for (int ch = 0; ch < 3; ++ch)
        #pragma unroll
        for (int j = 0; j < 4; ++j)
            res[ch][j] = bufA[ch * BUFP + (5 + row) * BUFW + (5 + colb + j)];

    // ---- 5 residual conv3x3 + leaky blocks (ping-pong LDS) ----
    float* src = bufA;
    float* dst = bufB;
    #pragma unroll
    for (int l = 0; l < 5; ++l) {
        const int o   = l + 1;               // region origin in buffer coords
        const int S   = BUFW - 2 * o;        // 40,38,36,34,32
        const int xs  = (S + 7) >> 3;        // 5,5,5,5,4
        const int d2  = (o - 1) & 1;         // window phase (keeps float2 loads aligned)
        const int bas = (o - 1) - d2;
        const int nst = S * xs;              // <=256 always
        if (tid < nst) {
            const int r  = tid / xs;
            const int c  = tid - r * xs;
            const int y  = o + r;
            const int x0 = o + c * 8;
            const int wv = (S - c * 8) < 8 ? (S - c * 8) : 8;
            const int gy = gy0 - 5 + y;

            float acc[3][8];
            #pragma unroll
            for (int oc = 0; oc < 3; ++oc) {
                float bia = wf[l * 84 + 81 + oc];
                #pragma unroll
                for (int px = 0; px < 8; ++px) acc[oc][px] = bia;
            }
            float cen[3][8];
            #pragma unroll
            for (int ic = 0; ic < 3; ++ic) {
                #pragma unroll
                for (int ky = 0; ky < 3; ++ky) {
                    float win[12];
                    const float* p = &src[ic * BUFP + (y - 1 + ky) * BUFW + bas + c * 8];
                    #pragma unroll
                    for (int t2 = 0; t2 < 6; ++t2) {
                        float2 v2 = *(const float2*)(p + 2 * t2);
                        win[2 * t2] = v2.x; win[2 * t2 + 1] = v2.y;
                    }
                    if (ky == 1) {
                        #pragma unroll
                        for (int px = 0; px < 8; ++px) cen[ic][px] = win[d2 + 1 + px];
                    }
                    #pragma unroll
                    for (int kx = 0; kx < 3; ++kx) {
                        #pragma unroll
                        for (int oc = 0; oc < 3; ++oc) {
                            float wv3 = wf[l * 84 + ((oc * 3 + ic) * 3 + ky) * 3 + kx];
                            #pragma unroll
                            for (int px = 0; px < 8; ++px)
                                acc[oc][px] += wv3 * win[d2 + kx + px];
                        }
                    }
                }
            }
            #pragma unroll
            for (int oc = 0; oc < 3; ++oc) {
                #pragma unroll
                for (int px = 0; px < 8; ++px) {
                    if (px < wv) {
                        float v = acc[oc][px] + cen[oc][px];
                        v = v >= 0.f ? v : 0.2f * v;
                        int gx = gx0 - 5 + x0 + px;
                        bool ok = ((unsigned)gy < 1024u) & ((unsigned)gx < 1024u);
                        dst[oc * BUFP + y * BUFW + x0 + px] = ok ? v : 0.f;
                    }
                }
            }
        }
        __syncthreads();
        float* t = src; src = dst; dst = t;
    }
    // after 5 swaps, conv3-chain result is in `src`

    // ---- epilogue: conv1x1 block + global residual + attention ----
    float x5v[3][4];
    #pragma unroll
    for (int ch = 0; ch < 3; ++ch)
        #pragma unroll
        for (int j = 0; j < 4; ++j)
            x5v[ch][j] = src[ch * BUFP + (5 + row) * BUFW + (5 + colb + j)];

    const int gy = gy0 + row;
    const float h1 = (float)gy * (1.0f / 1024.0f);
    float* outb = out + ((size_t)(b * 3) << 20);
    #pragma unroll
    for (int oc = 0; oc < 3; ++oc) {
        const float w10 = wf[420 + oc * 3 + 0];
        const float w11 = wf[420 + oc * 3 + 1];
        const float w12 = wf[420 + oc * 3 + 2];
        const float bb  = wf[429 + oc];
        const float* cf = wf + 432 + oc * 20;
        float tmp[4];
        #pragma unroll
        for (int j = 0; j < 4; ++j) {
            float s = x5v[oc][j] + bb + w10 * x5v[0][j] + w11 * x5v[1][j] + w12 * x5v[2][j];
            s = s >= 0.f ? s : 0.2f * s;
            float xf = res[oc][j] + s;
            float wc = (float)(gx0 + colb + j) * (1.0f / 1024.0f);
            float h2 = h1 * h1, h3 = h2 * h1;
            float w2 = wc * wc, w3 = w2 * wc;
            float x1 = xf, x2 = x1 * x1, x3 = x2 * x1;
            float att =
                cf[0] * h3 + cf[1] * h2 * wc + cf[2] * h2 * x1 + cf[3] * h2 +
                cf[4] * h1 * w2 + cf[5] * h1 * wc * x1 + cf[6] * h1 * wc + cf[7] * h1 * x2 +
                cf[8] * h1 * x1 + cf[9] * h1 + cf[10] * w3 + cf[11] * w2 * x1 + cf[12] * w2 +
                cf[13] * wc * x2 + cf[14] * wc * x1 + cf[15] * wc + cf[16] * x3 +
                cf[17] * x2 + cf[18] * x1 + cf[19];
            tmp[j] = xf * (1.f + att);
        }
        float4 vout = {tmp[0], tmp[1], tmp[2], tmp[3]};
        *(float4*)&outb[((size_t)oc << 20) + ((size_t)gy << 10) + (gx0 + colb)] = vout;
    }
}

extern "C" void kernel_launch(void* const* d_in, const int* in_sizes, int n_in,
                              void* d_out, int out_size, void* d_ws, size_t ws_size,
                              hipStream_t stream) {
    const float* x     = (const float*)d_in[0];
    const float* thumb = (const float*)d_in[1];
    const float* feat  = (const float*)d_in[2];
    float* out = (float*)d_out;

    dim3 grid(1024 / TILE, 1024 / TILE, 8);
    fused_net<<<grid, 256, 0, stream>>>(x, feat, out);

    // thumb_x passthrough: 8*3*256*256 floats appended after x_out
    hipMemcpyAsync(out + 25165824ull, thumb, 1572864ull * sizeof(float),
                   hipMemcpyDeviceToDevice, stream);
}

// Round 2
// 408.306 us; speedup vs baseline: 1.3751x; 1.3751x over previous
//
#include <hip/hip_runtime.h>

// Fused per-sample dynamic conv network, fp32.
// x: (8,3,1024,1024), thumb: (8,3,256,256), feature: (8,492)
// out = [x_out flat, thumb flat]
//
// One block = one 32x32 output tile of one sample, 512 threads (8 waves).
// R1: 256 thr -> 12 waves/CU theoretical, 23% achieved, VALUBusy 50% (latency-bound).
// R2: 512 thr/block keeps LDS/block constant -> 24 waves/CU theoretical (75%).
// Halo 5; LDS ping-pong 3x42x42 fp32; valid region shrinks 1/layer.
// conv1x1 + global residual + attention fused in epilogue.
// Thumb passthrough folded into same dispatch (blockIdx.x == 32 blocks).

#define TILE 32
#define BUFW 42
#define BUFP (BUFW*BUFW)      // 1764
#define BUFE (3*BUFP)         // 5292

__global__ __launch_bounds__(512, 6) void fused_net(
    const float* __restrict__ xin,
    const float* __restrict__ thumb,
    const float* __restrict__ feat,
    float* __restrict__ out)
{
    const int tid = threadIdx.x;

    // ---- thumb passthrough blocks (no LDS use, exit before barriers) ----
    if (blockIdx.x == 32) {
        const int part = blockIdx.y + 32 * blockIdx.z;     // 0..255
        const float4* s4 = (const float4*)thumb;
        float4* d4 = (float4*)(out + 25165824ull);
        const int n4 = 1572864 / 4;                        // 393216
        for (int i = part * 512 + tid; i < n4; i += 256 * 512)
            d4[i] = s4[i];
        return;
    }

    const int gx0 = blockIdx.x * TILE;
    const int gy0 = blockIdx.y * TILE;
    const int b   = blockIdx.z;
    const float* wf = feat + b * 492;   // uniform -> scalar loads

    __shared__ float lds[2 * BUFE + 16];
    float* bufA = lds;
    float* bufB = lds + BUFE + 8;       // pad absorbs benign OOB window reads

    // ---- stage input tile (halo 5, zero outside image) ----
    const float* xb = xin + ((size_t)(b * 3) << 20);
    for (int idx = tid; idx < BUFE; idx += 512) {
        int ch  = idx / BUFP;
        int rem = idx - ch * BUFP;
        int yy  = rem / BUFW;
        int xx  = rem - yy * BUFW;
        int gy = gy0 - 5 + yy, gx = gx0 - 5 + xx;
        float v = 0.f;
        if ((unsigned)gy < 1024u && (unsigned)gx < 1024u)
            v = xb[(ch << 20) + (gy << 10) + gx];
        bufA[idx] = v;
    }
    __syncthreads();

    // ---- residual (original x) for this thread's 2 fixed output pixels ----
    const int row  = tid >> 4;          // 0..31
    const int col2 = (tid & 15) << 1;   // 0,2,...,30
    float res[3][2];
    #pragma unroll
    for (int ch = 0; ch < 3; ++ch)
        #pragma unroll
        for (int j = 0; j < 2; ++j)
            res[ch][j] = bufA[ch * BUFP + (5 + row) * BUFW + (5 + col2 + j)];

    // ---- 5 residual conv3x3 + leaky blocks (ping-pong LDS) ----
    float* src = bufA;
    float* dst = bufB;
    #pragma unroll
    for (int l = 0; l < 5; ++l) {
        const int o   = l + 1;               // region origin in buffer coords
        const int S   = BUFW - 2 * o;        // 40,38,36,34,32
        const int xs  = (S + 3) >> 2;        // strips of 4: 10,10,9,9,8
        const int d2  = (o - 1) & 1;         // window phase (aligned float2 loads)
        const int bas = (o - 1) - d2;
        const int nst = S * xs;              // 400,380,324,306,256 <= 512
        if (tid < nst) {
            const int r  = tid / xs;
            const int c  = tid - r * xs;
            const int y  = o + r;
            const int x0 = o + c * 4;
            const int wv = (S - c * 4) < 4 ? (S - c * 4) : 4;
            const int gy = gy0 - 5 + y;

            float acc[3][4];
            #pragma unroll
            for (int oc = 0; oc < 3; ++oc) {
                float bia = wf[l * 84 + 81 + oc];
                #pragma unroll
                for (int px = 0; px < 4; ++px) acc[oc][px] = bia;
            }
            float cen[3][4];
            #pragma unroll
            for (int ic = 0; ic < 3; ++ic) {
                #pragma unroll
                for (int ky = 0; ky < 3; ++ky) {
                    float win[8];
                    const float* p = &src[ic * BUFP + (y - 1 + ky) * BUFW + bas + c * 4];
                    #pragma unroll
                    for (int t2 = 0; t2 < 4; ++t2) {
                        float2 v2 = *(const float2*)(p + 2 * t2);
                        win[2 * t2] = v2.x; win[2 * t2 + 1] = v2.y;
                    }
                    if (ky == 1) {
                        #pragma unroll
                        for (int px = 0; px < 4; ++px) cen[ic][px] = win[d2 + 1 + px];
                    }
                    #pragma unroll
                    for (int kx = 0; kx < 3; ++kx) {
                        #pragma unroll
                        for (int oc = 0; oc < 3; ++oc) {
                            float wv3 = wf[l * 84 + ((oc * 3 + ic) * 3 + ky) * 3 + kx];
                            #pragma unroll
                            for (int px = 0; px < 4; ++px)
                                acc[oc][px] += wv3 * win[d2 + kx + px];
                        }
                    }
                }
            }
            #pragma unroll
            for (int oc = 0; oc < 3; ++oc) {
                #pragma unroll
                for (int px = 0; px < 4; ++px) {
                    if (px < wv) {
                        float v = acc[oc][px] + cen[oc][px];
                        v = v >= 0.f ? v : 0.2f * v;
                        int gx = gx0 - 5 + x0 + px;
                        bool ok = ((unsigned)gy < 1024u) & ((unsigned)gx < 1024u);
                        dst[oc * BUFP + y * BUFW + x0 + px] = ok ? v : 0.f;
                    }
                }
            }
        }
        __syncthreads();
        float* t = src; src = dst; dst = t;
    }
    // after 5 swaps, conv3-chain result is in `src`

    // ---- epilogue: conv1x1 block + global residual + attention ----
    float x5v[3][2];
    #pragma unroll
    for (int ch = 0; ch < 3; ++ch)
        #pragma unroll
        for (int j = 0; j < 2; ++j)
            x5v[ch][j] = src[ch * BUFP + (5 + row) * BUFW + (5 + col2 + j)];

    const int gy = gy0 + row;
    const float h1 = (float)gy * (1.0f / 1024.0f);
    float* outb = out + ((size_t)(b * 3) << 20);
    #pragma unroll
    for (int oc = 0; oc < 3; ++oc) {
        const float w10 = wf[420 + oc * 3 + 0];
        const float w11 = wf[420 + oc * 3 + 1];
        const float w12 = wf[420 + oc * 3 + 2];
        const float bb  = wf[429 + oc];
        const float* cf = wf + 432 + oc * 20;
        float tmp[2];
        #pragma unroll
        for (int j = 0; j < 2; ++j) {
            float s = x5v[oc][j] + bb + w10 * x5v[0][j] + w11 * x5v[1][j] + w12 * x5v[2][j];
            s = s >= 0.f ? s : 0.2f * s;
            float xf = res[oc][j] + s;
            float wc = (float)(gx0 + col2 + j) * (1.0f / 1024.0f);
            float h2 = h1 * h1, h3 = h2 * h1;
            float w2 = wc * wc, w3 = w2 * wc;
            float x1 = xf, x2 = x1 * x1, x3 = x2 * x1;
            float att =
                cf[0] * h3 + cf[1] * h2 * wc + cf[2] * h2 * x1 + cf[3] * h2 +
                cf[4] * h1 * w2 + cf[5] * h1 * wc * x1 + cf[6] * h1 * wc + cf[7] * h1 * x2 +
                cf[8] * h1 * x1 + cf[9] * h1 + cf[10] * w3 + cf[11] * w2 * x1 + cf[12] * w2 +
                cf[13] * wc * x2 + cf[14] * wc * x1 + cf[15] * wc + cf[16] * x3 +
                cf[17] * x2 + cf[18] * x1 + cf[19];
            tmp[j] = xf * (1.f + att);
        }
        float2 vout = {tmp[0], tmp[1]};
        *(float2*)&outb[((size_t)oc << 20) + ((size_t)gy << 10) + (gx0 + col2)] = vout;
    }
}

extern "C" void kernel_launch(void* const* d_in, const int* in_sizes, int n_in,
                              void* d_out, int out_size, void* d_ws, size_t ws_size,
                              hipStream_t stream) {
    const float* x     = (const float*)d_in[0];
    const float* thumb = (const float*)d_in[1];
    const float* feat  = (const float*)d_in[2];
    float* out = (float*)d_out;

    dim3 grid(1024 / TILE + 1, 1024 / TILE, 8);   // x==32 blocks do the thumb copy
    fused_net<<<grid, 512, 0, stream>>>(x, thumb, feat, out);
}

// Round 5
// 299.417 us; speedup vs baseline: 1.8753x; 1.3637x over previous
//
#include <hip/hip_runtime.h>
#include <hip/hip_fp16.h>

typedef unsigned int uint;
typedef _Float16 h2 __attribute__((ext_vector_type(2)));

// Fused per-sample dynamic conv network.
// x: (8,3,1024,1024) f32, thumb: (8,3,256,256) f32, feature: (8,492) f32
// out = [x_out flat, thumb flat], f32.
//
// Conv chain in PACKED fp16 (v_pk_fma_f16 = 2x fp32 FMA rate) to break the
// fp32 VALU-issue wall (~540k cyc/CU). Weights pre-packed {w,w} per sample into
// d_ws by a prep kernel. fp16 via clang ext-vector _Float16 + elementwise
// builtins (ROCm header lacks __hmin2/__hmax2).
// LDS: half2 buffers, 42 rows x 23 dwords x 3ch, ping-pong = 23KB.
// Strips: 4 px/thread, even-aligned origins -> layer-uniform window phase.
// Epilogue (conv1x1 + residual + attention poly) in fp32.

#define ROWS   42
#define W_U    23            // dwords (half2) per row
#define CHP_U  (ROWS*W_U)    // 966 dwords per channel
#define BUF_U  (3*CHP_U)     // 2898 dwords per buffer

__device__ __forceinline__ h2   U2H(uint u) { return __builtin_bit_cast(h2, u); }
__device__ __forceinline__ uint H2U(h2 h)   { return __builtin_bit_cast(uint, h); }

// ---------------- prep: pack per-sample conv3 weights as {w,w} half2 ----------------
// table layout per sample (stride 448 dwords):
//   [0..404]   conv3 weights, idx = l*81 + ic*27 + ky*9 + oc*3 + kx
//   [405..419] conv3 bias,    idx = 405 + l*3 + oc
__global__ void prep_weights(const float* __restrict__ feat, uint* __restrict__ wtab)
{
    const int b = blockIdx.x;
    const int t = threadIdx.x;
    float w = 0.f;
    bool valid = false;
    if (t < 405) {
        int l = t / 81, r = t % 81;
        int ic = r / 27; r %= 27;
        int ky = r / 9;  r %= 9;
        int oc = r / 3;
        int kx = r % 3;
        w = feat[b * 492 + l * 84 + ((oc * 3 + ic) * 3 + ky) * 3 + kx];
        valid = true;
    } else if (t < 420) {
        int i = t - 405;
        w = feat[b * 492 + (i / 3) * 84 + 81 + (i % 3)];
        valid = true;
    }
    if (valid) {
        _Float16 h = (_Float16)w;
        h2 hh = { h, h };
        wtab[b * 448 + t] = H2U(hh);
    }
}

// ---------------- main fused kernel ----------------
__global__ __launch_bounds__(512, 8) void fused_net(
    const float* __restrict__ xin,
    const float* __restrict__ thumb,
    const float* __restrict__ feat,
    const uint*  __restrict__ wtab,
    float* __restrict__ out)
{
    const int tid = threadIdx.x;

    // ---- thumb passthrough blocks (whole block exits before any barrier) ----
    if (blockIdx.x == 32) {
        const int part = blockIdx.y + 32 * blockIdx.z;     // 0..255
        const float4* s4 = (const float4*)thumb;
        float4* d4 = (float4*)(out + 25165824ull);
        const int n4 = 1572864 / 4;
        for (int i = part * 512 + tid; i < n4; i += 256 * 512)
            d4[i] = s4[i];
        return;
    }

    const int gx0 = blockIdx.x * 32;
    const int gy0 = blockIdx.y * 32;
    const int b   = blockIdx.z;
    const float* wf = feat + b * 492;        // uniform fp32 (epilogue)
    const uint*  wt = wtab + b * 448;        // uniform packed half2 (conv)

    __shared__ uint lds[2 * BUF_U + 8];
    uint* b0 = lds;
    uint* b1 = lds + BUF_U + 4;

    // ---- stage: f32 global -> half2 LDS. half-lane j <-> gx = gx0-6+j ----
    const float* xb = xin + ((size_t)(b * 3) << 20);
    for (int idx = tid; idx < BUF_U; idx += 512) {
        int ch  = idx / CHP_U;
        int rem = idx - ch * CHP_U;
        int row = rem / W_U;
        int u   = rem - row * W_U;
        int gy = gy0 - 5 + row;
        int gx = gx0 - 6 + 2 * u;
        float f0 = 0.f, f1 = 0.f;
        if ((unsigned)gy < 1024u) {
            const float* rp = xb + (ch << 20) + (gy << 10);
            if ((unsigned)gx < 1024u)       f0 = rp[gx];
            if ((unsigned)(gx + 1) < 1024u) f1 = rp[gx + 1];
        }
        b0[idx] = __builtin_bit_cast(uint, __builtin_amdgcn_cvt_pkrtz(f0, f1));
    }
    __syncthreads();

    // ---- epilogue coords + pre-read residual (b0 is clobbered at l=1) ----
    const int erow = tid >> 4;               // 0..31
    const int col2 = (tid & 15) << 1;        // 0,2,...,30
    const int ub   = (5 + erow) * W_U + 3 + (col2 >> 1);
    uint resu[3];
    #pragma unroll
    for (int ch = 0; ch < 3; ++ch) resu[ch] = b0[ch * CHP_U + ub];

    const h2 c02 = { (_Float16)0.2f, (_Float16)0.2f };
    const h2 z2  = { (_Float16)0.f,  (_Float16)0.f  };

    // ---- 5 conv3x3 residual+leaky layers, packed fp16, ping-pong ----
    #pragma unroll
    for (int l = 0; l < 5; ++l) {
        uint* sb = (l & 1) ? b1 : b0;
        uint* db = (l & 1) ? b0 : b1;
        const int S   = 40 - 2 * l;
        const int xs  = (S + 3) >> 2;
        const int nst = S * xs;
        const int oy  = l + 1;
        const int EX  = (l + 2) & ~1;        // even strip origin (junk cols never re-read)
        if (tid < nst) {
            const int r  = tid / xs;
            const int c  = tid - r * xs;
            const int y  = oy + r;
            const int x0 = EX + 4 * c;       // even
            const int bu = (x0 >> 1) - 1;
            // out-of-image masks (zero = conv padding semantics for next layer)
            const int gy  = gy0 - 5 + y;
            const int gxA = gx0 - 6 + x0;
            const uint mrow = ((unsigned)gy < 1024u) ? 0xffffffffu : 0u;
            const uint mA = mrow & ((((unsigned)gxA       < 1024u) ? 0x0000ffffu : 0u) |
                                    (((unsigned)(gxA + 1) < 1024u) ? 0xffff0000u : 0u));
            const uint mB = mrow & ((((unsigned)(gxA + 2) < 1024u) ? 0x0000ffffu : 0u) |
                                    (((unsigned)(gxA + 3) < 1024u) ? 0xffff0000u : 0u));

            h2 accA[3], accB[3];
            #pragma unroll
            for (int oc = 0; oc < 3; ++oc) {
                h2 bi = U2H(wt[405 + l * 3 + oc]);
                accA[oc] = bi; accB[oc] = bi;
            }
            uint cA[3], cB[3];
            #pragma unroll
            for (int ic = 0; ic < 3; ++ic) {
                const int ai = ic * CHP_U + (y - 1) * W_U + bu;
                #pragma unroll
                for (int ky = 0; ky < 3; ++ky) {
                    const int a = ai + ky * W_U;
                    uint u0 = sb[a], u1 = sb[a + 1], u2 = sb[a + 2], u3 = sb[a + 3];
                    uint X01 = (u0 >> 16) | (u1 << 16);   // halves {1,2}
                    uint X12 = (u1 >> 16) | (u2 << 16);   // halves {3,4}
                    uint X23 = (u2 >> 16) | (u3 << 16);   // halves {5,6}
                    if (ky == 1) { cA[ic] = u1; cB[ic] = u2; }
                    const int wb = l * 81 + (ic * 3 + ky) * 9;
                    #pragma unroll
                    for (int oc = 0; oc < 3; ++oc) {
                        h2 w0 = U2H(wt[wb + oc * 3 + 0]);
                        h2 w1 = U2H(wt[wb + oc * 3 + 1]);
                        h2 w2 = U2H(wt[wb + oc * 3 + 2]);
                        accA[oc] = __builtin_elementwise_fma(w0, U2H(X01), accA[oc]);
                        accA[oc] = __builtin_elementwise_fma(w1, U2H(u1),  accA[oc]);
                        accA[oc] = __builtin_elementwise_fma(w2, U2H(X12), accA[oc]);
                        accB[oc] = __builtin_elementwise_fma(w0, U2H(X12), accB[oc]);
                        accB[oc] = __builtin_elementwise_fma(w1, U2H(u2),  accB[oc]);
                        accB[oc] = __builtin_elementwise_fma(w2, U2H(X23), accB[oc]);
                    }
                }
            }
            const int ob = y * W_U + (x0 >> 1);
            #pragma unroll
            for (int oc = 0; oc < 3; ++oc) {
                h2 vA = accA[oc] + U2H(cA[oc]);
                h2 vB = accB[oc] + U2H(cB[oc]);
                // leaky 0.2: max(v,0) + 0.2*min(v,0)  (v_pk_max/min/fma_f16)
                vA = __builtin_elementwise_fma(c02, __builtin_elementwise_min(vA, z2),
                                               __builtin_elementwise_max(vA, z2));
                vB = __builtin_elementwise_fma(c02, __builtin_elementwise_min(vB, z2),
                                               __builtin_elementwise_max(vB, z2));
                db[oc * CHP_U + ob]     = H2U(vA) & mA;
                db[oc * CHP_U + ob + 1] = H2U(vB) & mB;
            }
        }
        __syncthreads();
    }
    // final conv3 result is in b1

    // ---- epilogue: conv1x1 + global residual + attention (fp32) ----
    float x5f[3][2], resf[3][2];
    #pragma unroll
    for (int ch = 0; ch < 3; ++ch) {
        h2 hr = U2H(resu[ch]);
        resf[ch][0] = (float)hr.x; resf[ch][1] = (float)hr.y;
        h2 hx = U2H(b1[ch * CHP_U + ub]);
        x5f[ch][0] = (float)hx.x; x5f[ch][1] = (float)hx.y;
    }
    const int gy = gy0 + erow;
    const float h1 = (float)gy * (1.0f / 1024.0f);
    const float h2v = h1 * h1, h3 = h2v * h1;
    float* outb = out + ((size_t)(b * 3) << 20);
    float tmp[3][2];
    #pragma unroll
    for (int j = 0; j < 2; ++j) {
        const float wc = (float)(gx0 + col2 + j) * (1.0f / 1024.0f);
        const float w2 = wc * wc, w3 = w2 * wc;
        const float hw = h1 * wc, h2w = h2v * wc, hw2 = h1 * w2;
        #pragma unroll
        for (int oc = 0; oc < 3; ++oc) {
            float s = x5f[oc][j] + wf[429 + oc]
                    + wf[420 + oc * 3 + 0] * x5f[0][j]
                    + wf[420 + oc * 3 + 1] * x5f[1][j]
                    + wf[420 + oc * 3 + 2] * x5f[2][j];
            s = s >= 0.f ? s : 0.2f * s;
            const float xf = resf[oc][j] + s;
            const float x1 = xf, x2 = x1 * x1, x3 = x2 * x1;
            const float* cf = wf + 432 + oc * 20;
            float att =
                cf[0] * h3 + cf[1] * h2w + cf[2] * h2v * x1 + cf[3] * h2v +
                cf[4] * hw2 + cf[5] * hw * x1 + cf[6] * hw + cf[7] * h1 * x2 +
                cf[8] * h1 * x1 + cf[9] * h1 + cf[10] * w3 + cf[11] * w2 * x1 +
                cf[12] * w2 + cf[13] * wc * x2 + cf[14] * wc * x1 + cf[15] * wc +
                cf[16] * x3 + cf[17] * x2 + cf[18] * x1 + cf[19];
            tmp[oc][j] = xf * (1.f + att);
        }
    }
    #pragma unroll
    for (int oc = 0; oc < 3; ++oc) {
        float2 v = {tmp[oc][0], tmp[oc][1]};
        *(float2*)&outb[((size_t)oc << 20) + ((size_t)gy << 10) + (gx0 + col2)] = v;
    }
}

extern "C" void kernel_launch(void* const* d_in, const int* in_sizes, int n_in,
                              void* d_out, int out_size, void* d_ws, size_t ws_size,
                              hipStream_t stream) {
    const float* x     = (const float*)d_in[0];
    const float* thumb = (const float*)d_in[1];
    const float* feat  = (const float*)d_in[2];
    float* out = (float*)d_out;
    uint* wtab = (uint*)d_ws;   // 8 * 448 dwords = 14336 B

    prep_weights<<<dim3(8), 448, 0, stream>>>(feat, wtab);
    dim3 grid(33, 32, 8);       // x==32 blocks do the thumb copy
    fused_net<<<grid, 512, 0, stream>>>(x, thumb, feat, wtab, out);
}